// Round 11
// baseline (3673.146 us; speedup 1.0000x reference)
//
#include <hip/hip_runtime.h>

// h <- A_norm h, 12 times, in u-space (u = rsqrt(deg).*h):
//   u'[d] = (1/deg[d]) * (u[d] + sum_{s in N(d)} u[s]),  h12 = sqrt(deg).*u12
// EDGE-CENTRIC layers: sedge two-level-sorted into 64-node sub-buckets; each
// layer block owns 64 nodes, accumulates gathers into LDS acc[64][17] via
// ds_add_f32 (pad-17 kills bank conflicts), uniform edge stream -> zero
// divergence, 8 blocks/CU occupancy. No adj/rowptr/scans/padding at all.
// Isolated nodes zeroed at the END (they never propagate -> equivalent).

#define NB 256
#define SBSHIFT 8
#define SBSIZE 256
#define NSBP 512          // padded coarse bin count (nsb = 391 <= 512)
#define CH 4096           // edges per reorder chunk
#define RT 512            // reorder threads
#define EPT 8             // CH / RT

typedef int   v4i __attribute__((ext_vector_type(4)));
typedef float v4f __attribute__((ext_vector_type(4)));

__global__ void k_zero(int* __restrict__ sbhist, unsigned* __restrict__ mask, int nsb, int nm) {
    int i = blockIdx.x * NB + threadIdx.x;
    if (i < nsb) sbhist[i] = 0;
    if (i < nm) mask[i] = 0u;
}

__global__ void k_hist(const int* __restrict__ dst, int e, int* __restrict__ sbhist, int nsb) {
    __shared__ int lh[NSBP];
    for (int b = threadIdx.x; b < NSBP; b += NB) lh[b] = 0;
    __syncthreads();
    int stride = gridDim.x * NB;
    for (int i = blockIdx.x * NB + threadIdx.x; i < e; i += stride)
        atomicAdd(&lh[dst[i] >> SBSHIFT], 1);
    __syncthreads();
    for (int b = threadIdx.x; b < nsb; b += NB)
        if (lh[b]) atomicAdd(&sbhist[b], lh[b]);
}

__global__ __launch_bounds__(NSBP) void k_scan_sb(const int* __restrict__ sbhist,
                                                  int* __restrict__ sbbase,
                                                  int* __restrict__ bcur, int nsb) {
    __shared__ int sh[NSBP];
    int t = threadIdx.x;
    int v = (t < nsb) ? sbhist[t] : 0;
    sh[t] = v;
    __syncthreads();
    for (int off = 1; off < NSBP; off <<= 1) {
        int add = (t >= off) ? sh[t - off] : 0;
        __syncthreads();
        sh[t] += add;
        __syncthreads();
    }
    int incl = sh[t];
    if (t < nsb) { sbbase[t] = incl - v; bcur[t] = incl - v; }
    if (t == nsb - 1) sbbase[nsb] = incl;
}

// chunk-staged reorder: sedge[pos] = (src<<8)|(dst&255), coarse-bucket-sorted
__global__ __launch_bounds__(RT) void k_reorder(const int* __restrict__ src,
                                                const int* __restrict__ dst, int e,
                                                int* __restrict__ bcur, int* __restrict__ sedge) {
    __shared__ int lsize[NSBP];
    __shared__ int lscan[NSBP];
    __shared__ int ldelta[NSBP];
    __shared__ int lcur[NSBP];
    __shared__ int stage[CH];
    __shared__ int gpos[CH];
    int t = threadIdx.x;
    int base = blockIdx.x * CH;
    int cnt_here = e - base; if (cnt_here > CH) cnt_here = CH;
    lsize[t] = 0;
    __syncthreads();
    int myb[EPT], myw[EPT];
#pragma unroll
    for (int k = 0; k < EPT; ++k) {
        int i = base + k * RT + t;
        if (i < e) {
            int s = src[i], d = dst[i];
            int b = d >> SBSHIFT;
            myb[k] = b;
            myw[k] = (s << SBSHIFT) | (d & (SBSIZE - 1));
            atomicAdd(&lsize[b], 1);
        } else myb[k] = -1;
    }
    __syncthreads();
    int v = lsize[t];
    lscan[t] = v;
    __syncthreads();
    for (int off = 1; off < NSBP; off <<= 1) {
        int add = (t >= off) ? lscan[t - off] : 0;
        __syncthreads();
        lscan[t] += add;
        __syncthreads();
    }
    int excl = lscan[t] - v;
    if (v > 0) ldelta[t] = atomicAdd(&bcur[t], v) - excl;
    lcur[t] = excl;
    __syncthreads();
#pragma unroll
    for (int k = 0; k < EPT; ++k) {
        int b = myb[k];
        if (b >= 0) {
            int sl = atomicAdd(&lcur[b], 1);
            stage[sl] = myw[k];
            gpos[sl] = ldelta[b] + sl;
        }
    }
    __syncthreads();
    for (int s2 = t; s2 < cnt_here; s2 += RT)
        sedge[gpos[s2]] = stage[s2];
}

// second-level sort: coarse 256-bucket -> four 64-node sub-buckets.
// sedge2[pos] = (src<<6)|(dst&63); also emits cnt[] (per-node in-degree)
// and sbbase2[] (sub-bucket bases).
__global__ __launch_bounds__(NB) void k_subsort(const int* __restrict__ sedge,
                                                const int* __restrict__ sbbase,
                                                int* __restrict__ sedge2,
                                                int* __restrict__ sbbase2,
                                                int* __restrict__ cnt,
                                                int n, int e, int nsb) {
    __shared__ int c256[SBSIZE];
    __shared__ int c4[4];
    __shared__ int cur4[4];
    int t = threadIdx.x;
    int b = blockIdx.x;
    c256[t] = 0;
    if (t < 4) c4[t] = 0;
    __syncthreads();
    int lo = sbbase[b], hi = sbbase[b + 1];
    for (int i = lo + t; i < hi; i += NB) {
        int dl = sedge[i] & (SBSIZE - 1);
        atomicAdd(&c256[dl], 1);
        atomicAdd(&c4[dl >> 6], 1);
    }
    __syncthreads();
    if (t == 0) {
        int acc = lo;
        for (int s = 0; s < 4; ++s) {
            int v = c4[s];
            cur4[s] = acc;
            sbbase2[b * 4 + s] = acc;
            acc += v;
        }
    }
    int node = (b << SBSHIFT) + t;
    if (node < n) cnt[node] = c256[t];
    if (b == nsb - 1 && t == 0) sbbase2[nsb * 4] = e;
    __syncthreads();
    for (int i = lo + t; i < hi; i += NB) {
        int w = sedge[i];
        int dl = w & (SBSIZE - 1);
        int s = w >> SBSHIFT;
        int pos = atomicAdd(&cur4[dl >> 6], 1);
        sedge2[pos] = (s << 6) | (dl & 63);
    }
}

// mark nodes that appear as src but have indegree 0 (rare)
__global__ void k_mask(const int* __restrict__ src, const int* __restrict__ cnt,
                       unsigned* __restrict__ mask, int e) {
    int stride = gridDim.x * NB;
    for (int i = blockIdx.x * NB + threadIdx.x; i < e; i += stride) {
        int s = src[i];
        if (cnt[s] == 0) atomicOr(&mask[s >> 5], 1u << (s & 31));
    }
}

// u0 = x * rsqrt(deg) (no masking here; isolated zeroed in k_finish)
__global__ void k_init_u(const v4f* __restrict__ x, const int* __restrict__ cnt,
                         v4f* __restrict__ u, int n4) {
    int i = blockIdx.x * NB + threadIdx.x;
    if (i >= n4) return;
    int node = i >> 2;
    float is = rsqrtf((float)(cnt[node] + 1));
    u[i] = x[i] * is;
}

// edge-centric layer: block owns 64 nodes; quad-per-edge gathers u[src]
// (4 lanes x 16B = one 64B line) and ds_add_f32 into acc[64][17].
__global__ __launch_bounds__(NB) void k_layer_e(const int* __restrict__ sbbase2,
                                                const int* __restrict__ sedge2,
                                                const int* __restrict__ cnt,
                                                const v4f* __restrict__ u,
                                                v4f* __restrict__ un, int n) {
    __shared__ float acc[64 * 17];
    int t = threadIdx.x;
    int b = blockIdx.x;
    int nl = t >> 2, q = t & 3;
    int node = (b << 6) + nl;
    // init with self term (coefficient 1 in the u-space sum)
    v4f self = (v4f)(0.0f);
    if (node < n) self = u[(size_t)node * 4 + q];
    float* arow = acc + nl * 17 + q * 4;
    arow[0] = self.x; arow[1] = self.y; arow[2] = self.z; arow[3] = self.w;
    __syncthreads();
    int lo = sbbase2[b], hi = sbbase2[b + 1];
    int g = t >> 2;   // quad id 0..63
    for (int pbase = lo + g; pbase < hi; pbase += NB) {
        // unroll-4: up to 4 edges per quad in flight
        int e0 = pbase, e1 = pbase + 64, e2 = pbase + 128, e3 = pbase + 192;
        int w0 = (e0 < hi) ? sedge2[e0] : -1;
        int w1 = (e1 < hi) ? sedge2[e1] : -1;
        int w2 = (e2 < hi) ? sedge2[e2] : -1;
        int w3 = (e3 < hi) ? sedge2[e3] : -1;
        v4f g0 = (v4f)(0.0f), g1 = (v4f)(0.0f), g2 = (v4f)(0.0f), g3 = (v4f)(0.0f);
        if (w0 >= 0) g0 = u[(size_t)(w0 >> 6) * 4 + q];
        if (w1 >= 0) g1 = u[(size_t)(w1 >> 6) * 4 + q];
        if (w2 >= 0) g2 = u[(size_t)(w2 >> 6) * 4 + q];
        if (w3 >= 0) g3 = u[(size_t)(w3 >> 6) * 4 + q];
        if (w0 >= 0) {
            float* a = acc + (w0 & 63) * 17 + q * 4;
            atomicAdd(a + 0, g0.x); atomicAdd(a + 1, g0.y);
            atomicAdd(a + 2, g0.z); atomicAdd(a + 3, g0.w);
        }
        if (w1 >= 0) {
            float* a = acc + (w1 & 63) * 17 + q * 4;
            atomicAdd(a + 0, g1.x); atomicAdd(a + 1, g1.y);
            atomicAdd(a + 2, g1.z); atomicAdd(a + 3, g1.w);
        }
        if (w2 >= 0) {
            float* a = acc + (w2 & 63) * 17 + q * 4;
            atomicAdd(a + 0, g2.x); atomicAdd(a + 1, g2.y);
            atomicAdd(a + 2, g2.z); atomicAdd(a + 3, g2.w);
        }
        if (w3 >= 0) {
            float* a = acc + (w3 & 63) * 17 + q * 4;
            atomicAdd(a + 0, g3.x); atomicAdd(a + 1, g3.y);
            atomicAdd(a + 2, g3.z); atomicAdd(a + 3, g3.w);
        }
        pbase += 192;  // loop adds NB(256) total per iteration with the +=NB? no:
        // NOTE: stride handled here: we consumed 4*64 edges; loop's +=NB(256) completes it
        pbase -= 192;  // (keep canonical form: for-increment does +=256)
    }
    __syncthreads();
    if (node < n) {
        float c0 = 1.0f / (float)(cnt[node] + 1);
        v4f r;
        r.x = arow[0] * c0; r.y = arow[1] * c0;
        r.z = arow[2] * c0; r.w = arow[3] * c0;
        un[(size_t)node * 4 + q] = r;
    }
}

// h12 = sqrt(deg).*u12, zero if isolated (cnt==0 and never seen as src)
__global__ void k_finish(v4f* __restrict__ h, const int* __restrict__ cnt,
                         const unsigned* __restrict__ mask, int n4) {
    int i = blockIdx.x * NB + threadIdx.x;
    if (i >= n4) return;
    int node = i >> 2;
    int c = cnt[node];
    bool nonisol = (c > 0) || (((mask[node >> 5] >> (node & 31)) & 1u) != 0u);
    float s = nonisol ? sqrtf((float)(c + 1)) : 0.0f;
    h[i] = h[i] * s;
}

extern "C" void kernel_launch(void* const* d_in, const int* in_sizes, int n_in,
                              void* d_out, int out_size, void* d_ws, size_t ws_size,
                              hipStream_t stream) {
    const float* x  = (const float*)d_in[0];
    const int*   ei = (const int*)d_in[1];
    const int n = in_sizes[0] / 16;   // 100000
    const int e = in_sizes[1] / 2;    // 3200000
    const int* src = ei;
    const int* dst = ei + e;
    const int nm   = (n + 31) / 32;
    const int nsb  = (n + SBSIZE - 1) >> SBSHIFT;   // 391 coarse buckets
    const int nsb2 = nsb * 4;                        // 1564 sub-buckets

    char* ws = (char*)d_ws;
    auto take = [&](size_t bytes) {
        char* p = ws;
        ws += (bytes + 255) & ~(size_t)255;
        return p;
    };
    int*      sbhist  = (int*)take((size_t)NSBP * sizeof(int));
    int*      sbbase  = (int*)take((size_t)(NSBP + 1) * sizeof(int));
    int*      bcur    = (int*)take((size_t)NSBP * sizeof(int));
    int*      sbbase2 = (int*)take((size_t)(nsb2 + 1) * sizeof(int));
    unsigned* mask    = (unsigned*)take((size_t)nm * sizeof(unsigned));
    int*      cnt     = (int*)take((size_t)n * sizeof(int));
    int*      sedge   = (int*)take((size_t)e * sizeof(int));
    int*      sedge2  = (int*)take((size_t)e * sizeof(int));
    float*    uws     = (float*)take((size_t)n * 16 * sizeof(float));
    float*    uout    = (float*)d_out;

    const int gn4 = (n * 4 + NB - 1) / NB;   // 1563
    const int gre = (e + CH - 1) / CH;       // 782
    const int gz  = (((nsb > nm) ? nsb : nm) + NB - 1) / NB;

    k_zero<<<gz, NB, 0, stream>>>(sbhist, mask, nsb, nm);
    k_hist<<<512, NB, 0, stream>>>(dst, e, sbhist, nsb);
    k_scan_sb<<<1, NSBP, 0, stream>>>(sbhist, sbbase, bcur, nsb);
    k_reorder<<<gre, RT, 0, stream>>>(src, dst, e, bcur, sedge);
    k_subsort<<<nsb, NB, 0, stream>>>(sedge, sbbase, sedge2, sbbase2, cnt, n, e, nsb);
    k_mask<<<512, NB, 0, stream>>>(src, cnt, mask, e);
    k_init_u<<<gn4, NB, 0, stream>>>((const v4f*)x, cnt, (v4f*)uout, n * 4);

    float* cur = uout;   // 12 layers (even) -> result ends in d_out
    float* nxt = uws;
    for (int l = 0; l < 12; ++l) {
        k_layer_e<<<nsb2, NB, 0, stream>>>(sbbase2, sedge2, cnt,
                                           (const v4f*)cur, (v4f*)nxt, n);
        float* tp = cur; cur = nxt; nxt = tp;
    }
    k_finish<<<gn4, NB, 0, stream>>>((v4f*)uout, cnt, mask, n * 4);
}

// Round 12
// 565.860 us; speedup vs baseline: 6.4913x; 6.4913x over previous
//
#include <hip/hip_runtime.h>

// h <- A_norm h, 12 times, in u-space (u = rsqrt(deg).*h):
//   u'[d] = (1/deg[d]) * (u[d] + sum_{s in N(d)} u[s]),  h12 = sqrt(deg).*u12
// CSR built per call (bucketed, atomic-light). Layer kernel: node-centric,
// 4 lanes/node (one 64B line per gathered node, fully used), plain int4 adj
// loads (nt hurts: sub-line sequential stream), 8 gathers in flight, natural
// node order (R6: sorting loses locality), plain stores (R7: nt-store makes
// next layer miss). This is the measured optimum of 6 structural variants:
// the layer sits at the L2-miss/LLC-fill path limit (~131MB @ ~3.2TB/s).
// Isolated nodes zeroed at the END (they never propagate -> equivalent).

#define NB 256
#define SBSHIFT 8
#define SBSIZE 256
#define NSBP 512          // padded bin count (nsb = ceil(n/256) = 391 <= 512)
#define CH 4096           // edges per reorder chunk
#define RT 512            // reorder threads
#define EPT 8             // CH / RT

typedef int   v4i __attribute__((ext_vector_type(4)));
typedef float v4f __attribute__((ext_vector_type(4)));

__global__ void k_zero(int* __restrict__ sbhist, unsigned* __restrict__ mask, int nsb, int nm) {
    int i = blockIdx.x * NB + threadIdx.x;
    if (i < nsb) sbhist[i] = 0;
    if (i < nm) mask[i] = 0u;
}

__global__ void k_hist(const int* __restrict__ dst, int e, int* __restrict__ sbhist, int nsb) {
    __shared__ int lh[NSBP];
    for (int b = threadIdx.x; b < NSBP; b += NB) lh[b] = 0;
    __syncthreads();
    int stride = gridDim.x * NB;
    for (int i = blockIdx.x * NB + threadIdx.x; i < e; i += stride)
        atomicAdd(&lh[dst[i] >> SBSHIFT], 1);
    __syncthreads();
    for (int b = threadIdx.x; b < nsb; b += NB)
        if (lh[b]) atomicAdd(&sbhist[b], lh[b]);
}

__global__ __launch_bounds__(NSBP) void k_scan_sb(const int* __restrict__ sbhist,
                                                  int* __restrict__ sbbase,
                                                  int* __restrict__ bcur, int nsb) {
    __shared__ int sh[NSBP];
    int t = threadIdx.x;
    int v = (t < nsb) ? sbhist[t] : 0;
    sh[t] = v;
    __syncthreads();
    for (int off = 1; off < NSBP; off <<= 1) {
        int add = (t >= off) ? sh[t - off] : 0;
        __syncthreads();
        sh[t] += add;
        __syncthreads();
    }
    int incl = sh[t];
    if (t < nsb) { sbbase[t] = incl - v; bcur[t] = incl - v; }
    if (t == nsb - 1) sbbase[nsb] = incl;
}

// chunk-staged reorder: sedge[pos] = (src<<8)|(dst&255), bucket-sorted
__global__ __launch_bounds__(RT) void k_reorder(const int* __restrict__ src,
                                                const int* __restrict__ dst, int e,
                                                int* __restrict__ bcur, int* __restrict__ sedge) {
    __shared__ int lsize[NSBP];
    __shared__ int lscan[NSBP];
    __shared__ int ldelta[NSBP];
    __shared__ int lcur[NSBP];
    __shared__ int stage[CH];
    __shared__ int gpos[CH];
    int t = threadIdx.x;
    int base = blockIdx.x * CH;
    int cnt_here = e - base; if (cnt_here > CH) cnt_here = CH;
    lsize[t] = 0;
    __syncthreads();
    int myb[EPT], myw[EPT];
#pragma unroll
    for (int k = 0; k < EPT; ++k) {
        int i = base + k * RT + t;
        if (i < e) {
            int s = src[i], d = dst[i];
            int b = d >> SBSHIFT;
            myb[k] = b;
            myw[k] = (s << SBSHIFT) | (d & (SBSIZE - 1));
            atomicAdd(&lsize[b], 1);
        } else myb[k] = -1;
    }
    __syncthreads();
    int v = lsize[t];
    lscan[t] = v;
    __syncthreads();
    for (int off = 1; off < NSBP; off <<= 1) {
        int add = (t >= off) ? lscan[t - off] : 0;
        __syncthreads();
        lscan[t] += add;
        __syncthreads();
    }
    int excl = lscan[t] - v;
    if (v > 0) ldelta[t] = atomicAdd(&bcur[t], v) - excl;
    lcur[t] = excl;
    __syncthreads();
#pragma unroll
    for (int k = 0; k < EPT; ++k) {
        int b = myb[k];
        if (b >= 0) {
            int sl = atomicAdd(&lcur[b], 1);
            stage[sl] = myw[k];
            gpos[sl] = ldelta[b] + sl;
        }
    }
    __syncthreads();
    for (int s2 = t; s2 < cnt_here; s2 += RT)
        sedge[gpos[s2]] = stage[s2];
}

// per-bucket degree count + fused block-reduction of padded counts (scan1)
__global__ __launch_bounds__(SBSIZE) void k_fine_cnt(const int* __restrict__ sedge,
                                                     const int* __restrict__ sbbase,
                                                     int* __restrict__ cnt,
                                                     int* __restrict__ partial, int n) {
    __shared__ int lc[SBSIZE];
    __shared__ int red[SBSIZE];
    int t = threadIdx.x;
    lc[t] = 0;
    __syncthreads();
    int lo = sbbase[blockIdx.x], hi = sbbase[blockIdx.x + 1];
    for (int i = lo + t; i < hi; i += SBSIZE)
        atomicAdd(&lc[sedge[i] & (SBSIZE - 1)], 1);
    __syncthreads();
    int node = (blockIdx.x << SBSHIFT) + t;
    int c = lc[t];
    if (node < n) cnt[node] = c;
    red[t] = (node < n) ? ((c + 3) & ~3) : 0;
    __syncthreads();
    for (int s = SBSIZE / 2; s > 0; s >>= 1) {
        if (t < s) red[t] += red[t + s];
        __syncthreads();
    }
    if (t == 0) partial[blockIdx.x] = red[0];
}

__global__ void k_scan2(int* __restrict__ partial, int nb) {
    __shared__ int sd[512];
    int t = threadIdx.x;
    int v = (t < nb) ? partial[t] : 0;
    sd[t] = v;
    __syncthreads();
    for (int off = 1; off < 512; off <<= 1) {
        int add = (t >= off) ? sd[t - off] : 0;
        __syncthreads();
        sd[t] += add;
        __syncthreads();
    }
    if (t < nb) partial[t] = sd[t] - v;   // exclusive
}

__global__ void k_scan3(const int* __restrict__ cnt, const int* __restrict__ partial,
                        int* __restrict__ rowptr, int n) {
    __shared__ int sd[NB];
    int i = blockIdx.x * NB + threadIdx.x;
    int v = (i < n) ? ((cnt[i] + 3) & ~3) : 0;
    sd[threadIdx.x] = v;
    __syncthreads();
    for (int off = 1; off < NB; off <<= 1) {
        int add = (threadIdx.x >= off) ? sd[threadIdx.x - off] : 0;
        __syncthreads();
        sd[threadIdx.x] += add;
        __syncthreads();
    }
    int ex = sd[threadIdx.x] - v + partial[blockIdx.x];
    if (i < n) rowptr[i] = ex;
    if (i == n - 1) rowptr[n] = ex + v;
}

// per-bucket place via LDS cursors; pad slots filled in epilogue
__global__ __launch_bounds__(SBSIZE) void k_place(const int* __restrict__ sedge,
                                                  const int* __restrict__ sbbase,
                                                  const int* __restrict__ rowptr,
                                                  const int* __restrict__ cnt,
                                                  unsigned* __restrict__ mask,
                                                  int* __restrict__ adj, int n) {
    __shared__ int lcur[SBSIZE];
    int t = threadIdx.x;
    int node = (blockIdx.x << SBSHIFT) + t;
    lcur[t] = (node < n) ? rowptr[node] : 0;
    __syncthreads();
    int lo = sbbase[blockIdx.x], hi = sbbase[blockIdx.x + 1];
    for (int i = lo + t; i < hi; i += SBSIZE) {
        int w = sedge[i];
        int d = w & (SBSIZE - 1);
        int s = w >> SBSHIFT;
        int pos = atomicAdd(&lcur[d], 1);
        adj[pos] = s;
        if (cnt[s] == 0) atomicOr(&mask[s >> 5], 1u << (s & 31));  // rare
    }
    __syncthreads();
    if (node < n) {
        int en = rowptr[node + 1];
        for (int p = lcur[t]; p < en; ++p) adj[p] = node;  // lcur[t]==rowptr+cnt
    }
}

// u0 = x * rsqrt(deg) (no masking here; isolated zeroed in k_finish)
__global__ void k_init_u(const v4f* __restrict__ x, const int* __restrict__ cnt,
                         v4f* __restrict__ u, int n4) {
    int i = blockIdx.x * NB + threadIdx.x;
    if (i >= n4) return;
    int node = i >> 2;
    float is = rsqrtf((float)(cnt[node] + 1));
    u[i] = x[i] * is;
}

// 4 threads per node; lane q owns float4 quadrant q. 8 gathers in flight.
__global__ void k_layer(const int* __restrict__ rowptr, const int* __restrict__ cnt,
                        const int* __restrict__ adj,
                        const v4f* __restrict__ u, v4f* __restrict__ un, int n) {
    int t = blockIdx.x * NB + threadIdx.x;
    int node = t >> 2, q = t & 3;
    if (node >= n) return;
    int beg = rowptr[node], endp = rowptr[node + 1];
    int deg = cnt[node];
    float corr = (float)(1 - (endp - beg - deg));   // 1 - pads
    float c0 = 1.0f / (float)(deg + 1);
    v4f self = u[(size_t)node * 4 + q];
    v4f accA = (v4f)(0.0f);
    v4f accB = (v4f)(0.0f);
    int p = beg;
    for (; p + 8 <= endp; p += 8) {
        v4i sa = *(const v4i*)(adj + p);
        v4i sb = *(const v4i*)(adj + p + 4);
        v4f v0 = u[(size_t)sa.x * 4 + q];
        v4f v1 = u[(size_t)sa.y * 4 + q];
        v4f v2 = u[(size_t)sa.z * 4 + q];
        v4f v3 = u[(size_t)sa.w * 4 + q];
        v4f w0 = u[(size_t)sb.x * 4 + q];
        v4f w1 = u[(size_t)sb.y * 4 + q];
        v4f w2 = u[(size_t)sb.z * 4 + q];
        v4f w3 = u[(size_t)sb.w * 4 + q];
        accA += (v0 + v1) + (v2 + v3);
        accB += (w0 + w1) + (w2 + w3);
    }
    if (p < endp) {
        v4i sa = *(const v4i*)(adj + p);
        v4f v0 = u[(size_t)sa.x * 4 + q];
        v4f v1 = u[(size_t)sa.y * 4 + q];
        v4f v2 = u[(size_t)sa.z * 4 + q];
        v4f v3 = u[(size_t)sa.w * 4 + q];
        accA += (v0 + v1) + (v2 + v3);
    }
    v4f r = (accA + accB + corr * self) * c0;
    un[(size_t)node * 4 + q] = r;
}

// h12 = sqrt(deg).*u12, zero if isolated (cnt==0 and never seen as src)
__global__ void k_finish(v4f* __restrict__ h, const int* __restrict__ cnt,
                         const unsigned* __restrict__ mask, int n4) {
    int i = blockIdx.x * NB + threadIdx.x;
    if (i >= n4) return;
    int node = i >> 2;
    int c = cnt[node];
    bool nonisol = (c > 0) || (((mask[node >> 5] >> (node & 31)) & 1u) != 0u);
    float s = nonisol ? sqrtf((float)(c + 1)) : 0.0f;
    h[i] = h[i] * s;
}

extern "C" void kernel_launch(void* const* d_in, const int* in_sizes, int n_in,
                              void* d_out, int out_size, void* d_ws, size_t ws_size,
                              hipStream_t stream) {
    const float* x  = (const float*)d_in[0];
    const int*   ei = (const int*)d_in[1];
    const int n = in_sizes[0] / 16;   // 100000
    const int e = in_sizes[1] / 2;    // 3200000
    const int* src = ei;
    const int* dst = ei + e;
    const int nm  = (n + 31) / 32;
    const int nsb = (n + SBSIZE - 1) >> SBSHIFT;   // 391

    char* ws = (char*)d_ws;
    auto take = [&](size_t bytes) {
        char* p = ws;
        ws += (bytes + 255) & ~(size_t)255;
        return p;
    };
    int*      sbhist  = (int*)take((size_t)NSBP * sizeof(int));
    int*      sbbase  = (int*)take((size_t)(NSBP + 1) * sizeof(int));
    int*      bcur    = (int*)take((size_t)NSBP * sizeof(int));
    unsigned* mask    = (unsigned*)take((size_t)nm * sizeof(unsigned));
    int*      cnt     = (int*)take((size_t)n * sizeof(int));
    int*      rowptr  = (int*)take((size_t)(n + 1) * sizeof(int));
    int*      partial = (int*)take(512 * sizeof(int));
    int*      sedge   = (int*)take((size_t)e * sizeof(int));
    int*      adj     = (int*)take((size_t)(e + 4 * n) * sizeof(int));
    float*    uws     = (float*)take((size_t)n * 16 * sizeof(float));
    float*    uout    = (float*)d_out;

    const int gn  = (n + NB - 1) / NB;       // 391
    const int gn4 = (n * 4 + NB - 1) / NB;   // 1563
    const int gre = (e + CH - 1) / CH;       // 782
    const int gz  = (((nsb > nm) ? nsb : nm) + NB - 1) / NB;

    k_zero<<<gz, NB, 0, stream>>>(sbhist, mask, nsb, nm);
    k_hist<<<512, NB, 0, stream>>>(dst, e, sbhist, nsb);
    k_scan_sb<<<1, NSBP, 0, stream>>>(sbhist, sbbase, bcur, nsb);
    k_reorder<<<gre, RT, 0, stream>>>(src, dst, e, bcur, sedge);
    k_fine_cnt<<<nsb, SBSIZE, 0, stream>>>(sedge, sbbase, cnt, partial, n);
    k_scan2<<<1, 512, 0, stream>>>(partial, gn);
    k_scan3<<<gn, NB, 0, stream>>>(cnt, partial, rowptr, n);
    k_place<<<nsb, SBSIZE, 0, stream>>>(sedge, sbbase, rowptr, cnt, mask, adj, n);
    k_init_u<<<gn4, NB, 0, stream>>>((const v4f*)x, cnt, (v4f*)uout, n * 4);

    float* cur = uout;   // 12 layers (even) -> result ends in d_out
    float* nxt = uws;
    for (int l = 0; l < 12; ++l) {
        k_layer<<<gn4, NB, 0, stream>>>(rowptr, cnt, adj, (const v4f*)cur, (v4f*)nxt, n);
        float* tp = cur; cur = nxt; nxt = tp;
    }
    k_finish<<<gn4, NB, 0, stream>>>((v4f*)uout, cnt, mask, n * 4);
}

// Round 13
// 546.441 us; speedup vs baseline: 6.7220x; 1.0355x over previous
//
#include <hip/hip_runtime.h>

// h <- A_norm h, 12 times, in u-space (u = rsqrt(deg).*h):
//   u'[d] = (1/deg[d]) * (u[d] + sum_{s in N(d)} u[s]),  h12 = sqrt(deg).*u12
// CSR built per call. COLUMN-BLOCKED adjacency: each row stores src<n/2
// entries first (padded to x4), then src>=n/2 (padded to x4). Waves progress
// in near-lockstep, so each XCD's gather stream touches one 3.2MB half-table
// at a time -> reuse distance (50K lines) < L2 capacity (64K lines) -> the
// ~50MB/layer of capacity misses vanish. Layer kernel itself is UNCHANGED
// from the 566us champion (R12): worst case = identical behavior.
// Isolated nodes zeroed at the END (they never propagate -> equivalent).

#define NB 256
#define SBSHIFT 8
#define SBSIZE 256
#define NSBP 512          // padded bin count (nsb = ceil(n/256) = 391 <= 512)
#define CH 4096           // edges per reorder chunk
#define RT 512            // reorder threads
#define EPT 8             // CH / RT

typedef int   v4i __attribute__((ext_vector_type(4)));
typedef float v4f __attribute__((ext_vector_type(4)));

__global__ void k_zero(int* __restrict__ sbhist, unsigned* __restrict__ mask, int nsb, int nm) {
    int i = blockIdx.x * NB + threadIdx.x;
    if (i < nsb) sbhist[i] = 0;
    if (i < nm) mask[i] = 0u;
}

__global__ void k_hist(const int* __restrict__ dst, int e, int* __restrict__ sbhist, int nsb) {
    __shared__ int lh[NSBP];
    for (int b = threadIdx.x; b < NSBP; b += NB) lh[b] = 0;
    __syncthreads();
    int stride = gridDim.x * NB;
    for (int i = blockIdx.x * NB + threadIdx.x; i < e; i += stride)
        atomicAdd(&lh[dst[i] >> SBSHIFT], 1);
    __syncthreads();
    for (int b = threadIdx.x; b < nsb; b += NB)
        if (lh[b]) atomicAdd(&sbhist[b], lh[b]);
}

__global__ __launch_bounds__(NSBP) void k_scan_sb(const int* __restrict__ sbhist,
                                                  int* __restrict__ sbbase,
                                                  int* __restrict__ bcur, int nsb) {
    __shared__ int sh[NSBP];
    int t = threadIdx.x;
    int v = (t < nsb) ? sbhist[t] : 0;
    sh[t] = v;
    __syncthreads();
    for (int off = 1; off < NSBP; off <<= 1) {
        int add = (t >= off) ? sh[t - off] : 0;
        __syncthreads();
        sh[t] += add;
        __syncthreads();
    }
    int incl = sh[t];
    if (t < nsb) { sbbase[t] = incl - v; bcur[t] = incl - v; }
    if (t == nsb - 1) sbbase[nsb] = incl;
}

// chunk-staged reorder: sedge[pos] = (src<<8)|(dst&255), bucket-sorted
__global__ __launch_bounds__(RT) void k_reorder(const int* __restrict__ src,
                                                const int* __restrict__ dst, int e,
                                                int* __restrict__ bcur, int* __restrict__ sedge) {
    __shared__ int lsize[NSBP];
    __shared__ int lscan[NSBP];
    __shared__ int ldelta[NSBP];
    __shared__ int lcur[NSBP];
    __shared__ int stage[CH];
    __shared__ int gpos[CH];
    int t = threadIdx.x;
    int base = blockIdx.x * CH;
    int cnt_here = e - base; if (cnt_here > CH) cnt_here = CH;
    lsize[t] = 0;
    __syncthreads();
    int myb[EPT], myw[EPT];
#pragma unroll
    for (int k = 0; k < EPT; ++k) {
        int i = base + k * RT + t;
        if (i < e) {
            int s = src[i], d = dst[i];
            int b = d >> SBSHIFT;
            myb[k] = b;
            myw[k] = (s << SBSHIFT) | (d & (SBSIZE - 1));
            atomicAdd(&lsize[b], 1);
        } else myb[k] = -1;
    }
    __syncthreads();
    int v = lsize[t];
    lscan[t] = v;
    __syncthreads();
    for (int off = 1; off < NSBP; off <<= 1) {
        int add = (t >= off) ? lscan[t - off] : 0;
        __syncthreads();
        lscan[t] += add;
        __syncthreads();
    }
    int excl = lscan[t] - v;
    if (v > 0) ldelta[t] = atomicAdd(&bcur[t], v) - excl;
    lcur[t] = excl;
    __syncthreads();
#pragma unroll
    for (int k = 0; k < EPT; ++k) {
        int b = myb[k];
        if (b >= 0) {
            int sl = atomicAdd(&lcur[b], 1);
            stage[sl] = myw[k];
            gpos[sl] = ldelta[b] + sl;
        }
    }
    __syncthreads();
    for (int s2 = t; s2 < cnt_here; s2 += RT)
        sedge[gpos[s2]] = stage[s2];
}

// per-bucket degree count (total + lo half) + fused reduction of padded sizes
__global__ __launch_bounds__(SBSIZE) void k_fine_cnt(const int* __restrict__ sedge,
                                                     const int* __restrict__ sbbase,
                                                     int* __restrict__ cnt,
                                                     int* __restrict__ cntLo,
                                                     int* __restrict__ partial,
                                                     int n, int half) {
    __shared__ int lc[SBSIZE];
    __shared__ int lcLo[SBSIZE];
    __shared__ int red[SBSIZE];
    int t = threadIdx.x;
    lc[t] = 0; lcLo[t] = 0;
    __syncthreads();
    int lo = sbbase[blockIdx.x], hi = sbbase[blockIdx.x + 1];
    for (int i = lo + t; i < hi; i += SBSIZE) {
        int w = sedge[i];
        int dl = w & (SBSIZE - 1);
        atomicAdd(&lc[dl], 1);
        if ((w >> SBSHIFT) < half) atomicAdd(&lcLo[dl], 1);
    }
    __syncthreads();
    int node = (blockIdx.x << SBSHIFT) + t;
    int c = lc[t], cl = lcLo[t];
    int ch = c - cl;
    if (node < n) { cnt[node] = c; cntLo[node] = cl; }
    red[t] = (node < n) ? (((cl + 3) & ~3) + ((ch + 3) & ~3)) : 0;
    __syncthreads();
    for (int s = SBSIZE / 2; s > 0; s >>= 1) {
        if (t < s) red[t] += red[t + s];
        __syncthreads();
    }
    if (t == 0) partial[blockIdx.x] = red[0];
}

__global__ void k_scan2(int* __restrict__ partial, int nb) {
    __shared__ int sd[512];
    int t = threadIdx.x;
    int v = (t < nb) ? partial[t] : 0;
    sd[t] = v;
    __syncthreads();
    for (int off = 1; off < 512; off <<= 1) {
        int add = (t >= off) ? sd[t - off] : 0;
        __syncthreads();
        sd[t] += add;
        __syncthreads();
    }
    if (t < nb) partial[t] = sd[t] - v;   // exclusive
}

__global__ void k_scan3(const int* __restrict__ cnt, const int* __restrict__ cntLo,
                        const int* __restrict__ partial,
                        int* __restrict__ rowptr, int n) {
    __shared__ int sd[NB];
    int i = blockIdx.x * NB + threadIdx.x;
    int v = 0;
    if (i < n) {
        int cl = cntLo[i], ch = cnt[i] - cl;
        v = ((cl + 3) & ~3) + ((ch + 3) & ~3);
    }
    sd[threadIdx.x] = v;
    __syncthreads();
    for (int off = 1; off < NB; off <<= 1) {
        int add = (threadIdx.x >= off) ? sd[threadIdx.x - off] : 0;
        __syncthreads();
        sd[threadIdx.x] += add;
        __syncthreads();
    }
    int ex = sd[threadIdx.x] - v + partial[blockIdx.x];
    if (i < n) rowptr[i] = ex;
    if (i == n - 1) rowptr[n] = ex + v;
}

// per-bucket place with DUAL LDS cursors (lo-src region then hi-src region);
// pad slots (self-pointing) filled in epilogue.
__global__ __launch_bounds__(SBSIZE) void k_place(const int* __restrict__ sedge,
                                                  const int* __restrict__ sbbase,
                                                  const int* __restrict__ rowptr,
                                                  const int* __restrict__ cnt,
                                                  const int* __restrict__ cntLo,
                                                  unsigned* __restrict__ mask,
                                                  int* __restrict__ adj, int n, int half) {
    __shared__ int lcurLo[SBSIZE];
    __shared__ int lcurHi[SBSIZE];
    int t = threadIdx.x;
    int node = (blockIdx.x << SBSHIFT) + t;
    int rbeg = 0, loEnd = 0;
    if (node < n) {
        rbeg = rowptr[node];
        loEnd = rbeg + ((cntLo[node] + 3) & ~3);
    }
    lcurLo[t] = rbeg;
    lcurHi[t] = loEnd;
    __syncthreads();
    int lo = sbbase[blockIdx.x], hi = sbbase[blockIdx.x + 1];
    for (int i = lo + t; i < hi; i += SBSIZE) {
        int w = sedge[i];
        int d = w & (SBSIZE - 1);
        int s = w >> SBSHIFT;
        int pos = (s < half) ? atomicAdd(&lcurLo[d], 1) : atomicAdd(&lcurHi[d], 1);
        adj[pos] = s;
        if (cnt[s] == 0) atomicOr(&mask[s >> 5], 1u << (s & 31));  // rare
    }
    __syncthreads();
    if (node < n) {
        int en = rowptr[node + 1];
        for (int p = lcurLo[t]; p < loEnd; ++p) adj[p] = node;  // lo pads
        for (int p = lcurHi[t]; p < en; ++p) adj[p] = node;     // hi pads
    }
}

// u0 = x * rsqrt(deg) (no masking here; isolated zeroed in k_finish)
__global__ void k_init_u(const v4f* __restrict__ x, const int* __restrict__ cnt,
                         v4f* __restrict__ u, int n4) {
    int i = blockIdx.x * NB + threadIdx.x;
    if (i >= n4) return;
    int node = i >> 2;
    float is = rsqrtf((float)(cnt[node] + 1));
    u[i] = x[i] * is;
}

// 4 threads per node; lane q owns float4 quadrant q. 8 gathers in flight.
// (byte-identical logic to the R12 champion)
__global__ void k_layer(const int* __restrict__ rowptr, const int* __restrict__ cnt,
                        const int* __restrict__ adj,
                        const v4f* __restrict__ u, v4f* __restrict__ un, int n) {
    int t = blockIdx.x * NB + threadIdx.x;
    int node = t >> 2, q = t & 3;
    if (node >= n) return;
    int beg = rowptr[node], endp = rowptr[node + 1];
    int deg = cnt[node];
    float corr = (float)(1 - (endp - beg - deg));   // 1 - total pads
    float c0 = 1.0f / (float)(deg + 1);
    v4f self = u[(size_t)node * 4 + q];
    v4f accA = (v4f)(0.0f);
    v4f accB = (v4f)(0.0f);
    int p = beg;
    for (; p + 8 <= endp; p += 8) {
        v4i sa = *(const v4i*)(adj + p);
        v4i sb = *(const v4i*)(adj + p + 4);
        v4f v0 = u[(size_t)sa.x * 4 + q];
        v4f v1 = u[(size_t)sa.y * 4 + q];
        v4f v2 = u[(size_t)sa.z * 4 + q];
        v4f v3 = u[(size_t)sa.w * 4 + q];
        v4f w0 = u[(size_t)sb.x * 4 + q];
        v4f w1 = u[(size_t)sb.y * 4 + q];
        v4f w2 = u[(size_t)sb.z * 4 + q];
        v4f w3 = u[(size_t)sb.w * 4 + q];
        accA += (v0 + v1) + (v2 + v3);
        accB += (w0 + w1) + (w2 + w3);
    }
    if (p < endp) {
        v4i sa = *(const v4i*)(adj + p);
        v4f v0 = u[(size_t)sa.x * 4 + q];
        v4f v1 = u[(size_t)sa.y * 4 + q];
        v4f v2 = u[(size_t)sa.z * 4 + q];
        v4f v3 = u[(size_t)sa.w * 4 + q];
        accA += (v0 + v1) + (v2 + v3);
    }
    v4f r = (accA + accB + corr * self) * c0;
    un[(size_t)node * 4 + q] = r;
}

// h12 = sqrt(deg).*u12, zero if isolated (cnt==0 and never seen as src)
__global__ void k_finish(v4f* __restrict__ h, const int* __restrict__ cnt,
                         const unsigned* __restrict__ mask, int n4) {
    int i = blockIdx.x * NB + threadIdx.x;
    if (i >= n4) return;
    int node = i >> 2;
    int c = cnt[node];
    bool nonisol = (c > 0) || (((mask[node >> 5] >> (node & 31)) & 1u) != 0u);
    float s = nonisol ? sqrtf((float)(c + 1)) : 0.0f;
    h[i] = h[i] * s;
}

extern "C" void kernel_launch(void* const* d_in, const int* in_sizes, int n_in,
                              void* d_out, int out_size, void* d_ws, size_t ws_size,
                              hipStream_t stream) {
    const float* x  = (const float*)d_in[0];
    const int*   ei = (const int*)d_in[1];
    const int n = in_sizes[0] / 16;   // 100000
    const int e = in_sizes[1] / 2;    // 3200000
    const int* src = ei;
    const int* dst = ei + e;
    const int nm   = (n + 31) / 32;
    const int nsb  = (n + SBSIZE - 1) >> SBSHIFT;   // 391
    const int half = n / 2;                          // src column split

    char* ws = (char*)d_ws;
    auto take = [&](size_t bytes) {
        char* p = ws;
        ws += (bytes + 255) & ~(size_t)255;
        return p;
    };
    int*      sbhist  = (int*)take((size_t)NSBP * sizeof(int));
    int*      sbbase  = (int*)take((size_t)(NSBP + 1) * sizeof(int));
    int*      bcur    = (int*)take((size_t)NSBP * sizeof(int));
    unsigned* mask    = (unsigned*)take((size_t)nm * sizeof(unsigned));
    int*      cnt     = (int*)take((size_t)n * sizeof(int));
    int*      cntLo   = (int*)take((size_t)n * sizeof(int));
    int*      rowptr  = (int*)take((size_t)(n + 1) * sizeof(int));
    int*      partial = (int*)take(512 * sizeof(int));
    int*      sedge   = (int*)take((size_t)e * sizeof(int));
    int*      adj     = (int*)take((size_t)(e + 8 * n) * sizeof(int));
    float*    uws     = (float*)take((size_t)n * 16 * sizeof(float));
    float*    uout    = (float*)d_out;

    const int gn  = (n + NB - 1) / NB;       // 391
    const int gn4 = (n * 4 + NB - 1) / NB;   // 1563
    const int gre = (e + CH - 1) / CH;       // 782
    const int gz  = (((nsb > nm) ? nsb : nm) + NB - 1) / NB;

    k_zero<<<gz, NB, 0, stream>>>(sbhist, mask, nsb, nm);
    k_hist<<<512, NB, 0, stream>>>(dst, e, sbhist, nsb);
    k_scan_sb<<<1, NSBP, 0, stream>>>(sbhist, sbbase, bcur, nsb);
    k_reorder<<<gre, RT, 0, stream>>>(src, dst, e, bcur, sedge);
    k_fine_cnt<<<nsb, SBSIZE, 0, stream>>>(sedge, sbbase, cnt, cntLo, partial, n, half);
    k_scan2<<<1, 512, 0, stream>>>(partial, gn);
    k_scan3<<<gn, NB, 0, stream>>>(cnt, cntLo, partial, rowptr, n);
    k_place<<<nsb, SBSIZE, 0, stream>>>(sedge, sbbase, rowptr, cnt, cntLo, mask, adj, n, half);
    k_init_u<<<gn4, NB, 0, stream>>>((const v4f*)x, cnt, (v4f*)uout, n * 4);

    float* cur = uout;   // 12 layers (even) -> result ends in d_out
    float* nxt = uws;
    for (int l = 0; l < 12; ++l) {
        k_layer<<<gn4, NB, 0, stream>>>(rowptr, cnt, adj, (const v4f*)cur, (v4f*)nxt, n);
        float* tp = cur; cur = nxt; nxt = tp;
    }
    k_finish<<<gn4, NB, 0, stream>>>((v4f*)uout, cnt, mask, n * 4);
}

// Round 14
// 525.895 us; speedup vs baseline: 6.9846x; 1.0391x over previous
//
#include <hip/hip_runtime.h>

// h <- A_norm h, 12 times, in u-space (u = rsqrt(deg).*h):
//   u'[d] = (1/deg[d]) * (u[d] + sum_{s in N(d)} u[s]),  h12 = sqrt(deg).*u12
// CSR built per call, COLUMN-BLOCKED rows (src<n/2 region padded x4, then
// src>=n/2 region padded x4). Each layer = TWO dispatches:
//   pass A: un[d]  = sum over lo region (gathers touch only lo 3.2MB of u)
//   pass B: un[d] := (un[d] + sum over hi region + corr*self) / (deg+1)
// The kernel boundary enforces perfect phase separation (R13 showed in-row
// splits blur at thread granularity: rows are only ~4 MLP iterations), so
// each XCD's L2 holds one 3.2MB half-table per pass -> capacity misses ~0.
// Isolated nodes zeroed at the END (they never propagate -> equivalent).

#define NB 256
#define SBSHIFT 8
#define SBSIZE 256
#define NSBP 512          // padded bin count (nsb = ceil(n/256) = 391 <= 512)
#define CH 4096           // edges per reorder chunk
#define RT 512            // reorder threads
#define EPT 8             // CH / RT

typedef int   v4i __attribute__((ext_vector_type(4)));
typedef float v4f __attribute__((ext_vector_type(4)));

__global__ void k_zero(int* __restrict__ sbhist, unsigned* __restrict__ mask, int nsb, int nm) {
    int i = blockIdx.x * NB + threadIdx.x;
    if (i < nsb) sbhist[i] = 0;
    if (i < nm) mask[i] = 0u;
}

__global__ void k_hist(const int* __restrict__ dst, int e, int* __restrict__ sbhist, int nsb) {
    __shared__ int lh[NSBP];
    for (int b = threadIdx.x; b < NSBP; b += NB) lh[b] = 0;
    __syncthreads();
    int stride = gridDim.x * NB;
    for (int i = blockIdx.x * NB + threadIdx.x; i < e; i += stride)
        atomicAdd(&lh[dst[i] >> SBSHIFT], 1);
    __syncthreads();
    for (int b = threadIdx.x; b < nsb; b += NB)
        if (lh[b]) atomicAdd(&sbhist[b], lh[b]);
}

__global__ __launch_bounds__(NSBP) void k_scan_sb(const int* __restrict__ sbhist,
                                                  int* __restrict__ sbbase,
                                                  int* __restrict__ bcur, int nsb) {
    __shared__ int sh[NSBP];
    int t = threadIdx.x;
    int v = (t < nsb) ? sbhist[t] : 0;
    sh[t] = v;
    __syncthreads();
    for (int off = 1; off < NSBP; off <<= 1) {
        int add = (t >= off) ? sh[t - off] : 0;
        __syncthreads();
        sh[t] += add;
        __syncthreads();
    }
    int incl = sh[t];
    if (t < nsb) { sbbase[t] = incl - v; bcur[t] = incl - v; }
    if (t == nsb - 1) sbbase[nsb] = incl;
}

// chunk-staged reorder: sedge[pos] = (src<<8)|(dst&255), bucket-sorted
__global__ __launch_bounds__(RT) void k_reorder(const int* __restrict__ src,
                                                const int* __restrict__ dst, int e,
                                                int* __restrict__ bcur, int* __restrict__ sedge) {
    __shared__ int lsize[NSBP];
    __shared__ int lscan[NSBP];
    __shared__ int ldelta[NSBP];
    __shared__ int lcur[NSBP];
    __shared__ int stage[CH];
    __shared__ int gpos[CH];
    int t = threadIdx.x;
    int base = blockIdx.x * CH;
    int cnt_here = e - base; if (cnt_here > CH) cnt_here = CH;
    lsize[t] = 0;
    __syncthreads();
    int myb[EPT], myw[EPT];
#pragma unroll
    for (int k = 0; k < EPT; ++k) {
        int i = base + k * RT + t;
        if (i < e) {
            int s = src[i], d = dst[i];
            int b = d >> SBSHIFT;
            myb[k] = b;
            myw[k] = (s << SBSHIFT) | (d & (SBSIZE - 1));
            atomicAdd(&lsize[b], 1);
        } else myb[k] = -1;
    }
    __syncthreads();
    int v = lsize[t];
    lscan[t] = v;
    __syncthreads();
    for (int off = 1; off < NSBP; off <<= 1) {
        int add = (t >= off) ? lscan[t - off] : 0;
        __syncthreads();
        lscan[t] += add;
        __syncthreads();
    }
    int excl = lscan[t] - v;
    if (v > 0) ldelta[t] = atomicAdd(&bcur[t], v) - excl;
    lcur[t] = excl;
    __syncthreads();
#pragma unroll
    for (int k = 0; k < EPT; ++k) {
        int b = myb[k];
        if (b >= 0) {
            int sl = atomicAdd(&lcur[b], 1);
            stage[sl] = myw[k];
            gpos[sl] = ldelta[b] + sl;
        }
    }
    __syncthreads();
    for (int s2 = t; s2 < cnt_here; s2 += RT)
        sedge[gpos[s2]] = stage[s2];
}

// per-bucket degree count (total + lo half) + fused reduction of padded sizes
__global__ __launch_bounds__(SBSIZE) void k_fine_cnt(const int* __restrict__ sedge,
                                                     const int* __restrict__ sbbase,
                                                     int* __restrict__ cnt,
                                                     int* __restrict__ cntLo,
                                                     int* __restrict__ partial,
                                                     int n, int half) {
    __shared__ int lc[SBSIZE];
    __shared__ int lcLo[SBSIZE];
    __shared__ int red[SBSIZE];
    int t = threadIdx.x;
    lc[t] = 0; lcLo[t] = 0;
    __syncthreads();
    int lo = sbbase[blockIdx.x], hi = sbbase[blockIdx.x + 1];
    for (int i = lo + t; i < hi; i += SBSIZE) {
        int w = sedge[i];
        int dl = w & (SBSIZE - 1);
        atomicAdd(&lc[dl], 1);
        if ((w >> SBSHIFT) < half) atomicAdd(&lcLo[dl], 1);
    }
    __syncthreads();
    int node = (blockIdx.x << SBSHIFT) + t;
    int c = lc[t], cl = lcLo[t];
    int ch = c - cl;
    if (node < n) { cnt[node] = c; cntLo[node] = cl; }
    red[t] = (node < n) ? (((cl + 3) & ~3) + ((ch + 3) & ~3)) : 0;
    __syncthreads();
    for (int s = SBSIZE / 2; s > 0; s >>= 1) {
        if (t < s) red[t] += red[t + s];
        __syncthreads();
    }
    if (t == 0) partial[blockIdx.x] = red[0];
}

__global__ void k_scan2(int* __restrict__ partial, int nb) {
    __shared__ int sd[512];
    int t = threadIdx.x;
    int v = (t < nb) ? partial[t] : 0;
    sd[t] = v;
    __syncthreads();
    for (int off = 1; off < 512; off <<= 1) {
        int add = (t >= off) ? sd[t - off] : 0;
        __syncthreads();
        sd[t] += add;
        __syncthreads();
    }
    if (t < nb) partial[t] = sd[t] - v;   // exclusive
}

__global__ void k_scan3(const int* __restrict__ cnt, const int* __restrict__ cntLo,
                        const int* __restrict__ partial,
                        int* __restrict__ rowptr, int* __restrict__ rowptrLo, int n) {
    __shared__ int sd[NB];
    int i = blockIdx.x * NB + threadIdx.x;
    int v = 0, vlo = 0;
    if (i < n) {
        int cl = cntLo[i], ch = cnt[i] - cl;
        vlo = (cl + 3) & ~3;
        v = vlo + ((ch + 3) & ~3);
    }
    sd[threadIdx.x] = v;
    __syncthreads();
    for (int off = 1; off < NB; off <<= 1) {
        int add = (threadIdx.x >= off) ? sd[threadIdx.x - off] : 0;
        __syncthreads();
        sd[threadIdx.x] += add;
        __syncthreads();
    }
    int ex = sd[threadIdx.x] - v + partial[blockIdx.x];
    if (i < n) { rowptr[i] = ex; rowptrLo[i] = ex + vlo; }
    if (i == n - 1) rowptr[n] = ex + v;
}

// per-bucket place with DUAL LDS cursors (lo-src region then hi-src region);
// pad slots (self-pointing) filled in epilogue.
__global__ __launch_bounds__(SBSIZE) void k_place(const int* __restrict__ sedge,
                                                  const int* __restrict__ sbbase,
                                                  const int* __restrict__ rowptr,
                                                  const int* __restrict__ rowptrLo,
                                                  const int* __restrict__ cnt,
                                                  unsigned* __restrict__ mask,
                                                  int* __restrict__ adj, int n, int half) {
    __shared__ int lcurLo[SBSIZE];
    __shared__ int lcurHi[SBSIZE];
    int t = threadIdx.x;
    int node = (blockIdx.x << SBSHIFT) + t;
    int rbeg = 0, loEnd = 0;
    if (node < n) {
        rbeg = rowptr[node];
        loEnd = rowptrLo[node];
    }
    lcurLo[t] = rbeg;
    lcurHi[t] = loEnd;
    __syncthreads();
    int lo = sbbase[blockIdx.x], hi = sbbase[blockIdx.x + 1];
    for (int i = lo + t; i < hi; i += SBSIZE) {
        int w = sedge[i];
        int d = w & (SBSIZE - 1);
        int s = w >> SBSHIFT;
        int pos = (s < half) ? atomicAdd(&lcurLo[d], 1) : atomicAdd(&lcurHi[d], 1);
        adj[pos] = s;
        if (cnt[s] == 0) atomicOr(&mask[s >> 5], 1u << (s & 31));  // rare
    }
    __syncthreads();
    if (node < n) {
        int en = rowptr[node + 1];
        for (int p = lcurLo[t]; p < loEnd; ++p) adj[p] = node;  // lo pads
        for (int p = lcurHi[t]; p < en; ++p) adj[p] = node;     // hi pads
    }
}

// u0 = x * rsqrt(deg) (no masking here; isolated zeroed in k_finish)
__global__ void k_init_u(const v4f* __restrict__ x, const int* __restrict__ cnt,
                         v4f* __restrict__ u, int n4) {
    int i = blockIdx.x * NB + threadIdx.x;
    if (i >= n4) return;
    int node = i >> 2;
    float is = rsqrtf((float)(cnt[node] + 1));
    u[i] = x[i] * is;
}

// pass A: un[node] = sum over lo region (gathers hit only lo half of u)
__global__ void k_layerA(const int* __restrict__ rowptr, const int* __restrict__ rowptrLo,
                         const int* __restrict__ adj,
                         const v4f* __restrict__ u, v4f* __restrict__ un, int n) {
    int t = blockIdx.x * NB + threadIdx.x;
    int node = t >> 2, q = t & 3;
    if (node >= n) return;
    int beg = rowptr[node], endp = rowptrLo[node];
    v4f accA = (v4f)(0.0f);
    v4f accB = (v4f)(0.0f);
    int p = beg;
    for (; p + 8 <= endp; p += 8) {
        v4i sa = *(const v4i*)(adj + p);
        v4i sb = *(const v4i*)(adj + p + 4);
        v4f v0 = u[(size_t)sa.x * 4 + q];
        v4f v1 = u[(size_t)sa.y * 4 + q];
        v4f v2 = u[(size_t)sa.z * 4 + q];
        v4f v3 = u[(size_t)sa.w * 4 + q];
        v4f w0 = u[(size_t)sb.x * 4 + q];
        v4f w1 = u[(size_t)sb.y * 4 + q];
        v4f w2 = u[(size_t)sb.z * 4 + q];
        v4f w3 = u[(size_t)sb.w * 4 + q];
        accA += (v0 + v1) + (v2 + v3);
        accB += (w0 + w1) + (w2 + w3);
    }
    if (p < endp) {
        v4i sa = *(const v4i*)(adj + p);
        v4f v0 = u[(size_t)sa.x * 4 + q];
        v4f v1 = u[(size_t)sa.y * 4 + q];
        v4f v2 = u[(size_t)sa.z * 4 + q];
        v4f v3 = u[(size_t)sa.w * 4 + q];
        accA += (v0 + v1) + (v2 + v3);
    }
    un[(size_t)node * 4 + q] = accA + accB;
}

// pass B: un[node] = (un[node] + sum over hi region + corr*self) / (deg+1)
__global__ void k_layerB(const int* __restrict__ rowptr, const int* __restrict__ rowptrLo,
                         const int* __restrict__ cnt, const int* __restrict__ adj,
                         const v4f* __restrict__ u, v4f* __restrict__ un, int n) {
    int t = blockIdx.x * NB + threadIdx.x;
    int node = t >> 2, q = t & 3;
    if (node >= n) return;
    int beg = rowptrLo[node], endp = rowptr[node + 1];
    int rbeg = rowptr[node];
    int deg = cnt[node];
    float corr = (float)(1 - (endp - rbeg - deg));   // 1 - total pads
    float c0 = 1.0f / (float)(deg + 1);
    v4f self = u[(size_t)node * 4 + q];
    v4f accA = (v4f)(0.0f);
    v4f accB = (v4f)(0.0f);
    int p = beg;
    for (; p + 8 <= endp; p += 8) {
        v4i sa = *(const v4i*)(adj + p);
        v4i sb = *(const v4i*)(adj + p + 4);
        v4f v0 = u[(size_t)sa.x * 4 + q];
        v4f v1 = u[(size_t)sa.y * 4 + q];
        v4f v2 = u[(size_t)sa.z * 4 + q];
        v4f v3 = u[(size_t)sa.w * 4 + q];
        v4f w0 = u[(size_t)sb.x * 4 + q];
        v4f w1 = u[(size_t)sb.y * 4 + q];
        v4f w2 = u[(size_t)sb.z * 4 + q];
        v4f w3 = u[(size_t)sb.w * 4 + q];
        accA += (v0 + v1) + (v2 + v3);
        accB += (w0 + w1) + (w2 + w3);
    }
    if (p < endp) {
        v4i sa = *(const v4i*)(adj + p);
        v4f v0 = u[(size_t)sa.x * 4 + q];
        v4f v1 = u[(size_t)sa.y * 4 + q];
        v4f v2 = u[(size_t)sa.z * 4 + q];
        v4f v3 = u[(size_t)sa.w * 4 + q];
        accA += (v0 + v1) + (v2 + v3);
    }
    size_t oi = (size_t)node * 4 + q;
    v4f r = (un[oi] + accA + accB + corr * self) * c0;
    un[oi] = r;
}

// h12 = sqrt(deg).*u12, zero if isolated (cnt==0 and never seen as src)
__global__ void k_finish(v4f* __restrict__ h, const int* __restrict__ cnt,
                         const unsigned* __restrict__ mask, int n4) {
    int i = blockIdx.x * NB + threadIdx.x;
    if (i >= n4) return;
    int node = i >> 2;
    int c = cnt[node];
    bool nonisol = (c > 0) || (((mask[node >> 5] >> (node & 31)) & 1u) != 0u);
    float s = nonisol ? sqrtf((float)(c + 1)) : 0.0f;
    h[i] = h[i] * s;
}

extern "C" void kernel_launch(void* const* d_in, const int* in_sizes, int n_in,
                              void* d_out, int out_size, void* d_ws, size_t ws_size,
                              hipStream_t stream) {
    const float* x  = (const float*)d_in[0];
    const int*   ei = (const int*)d_in[1];
    const int n = in_sizes[0] / 16;   // 100000
    const int e = in_sizes[1] / 2;    // 3200000
    const int* src = ei;
    const int* dst = ei + e;
    const int nm   = (n + 31) / 32;
    const int nsb  = (n + SBSIZE - 1) >> SBSHIFT;   // 391
    const int half = n / 2;                          // src column split

    char* ws = (char*)d_ws;
    auto take = [&](size_t bytes) {
        char* p = ws;
        ws += (bytes + 255) & ~(size_t)255;
        return p;
    };
    int*      sbhist   = (int*)take((size_t)NSBP * sizeof(int));
    int*      sbbase   = (int*)take((size_t)(NSBP + 1) * sizeof(int));
    int*      bcur     = (int*)take((size_t)NSBP * sizeof(int));
    unsigned* mask     = (unsigned*)take((size_t)nm * sizeof(unsigned));
    int*      cnt      = (int*)take((size_t)n * sizeof(int));
    int*      cntLo    = (int*)take((size_t)n * sizeof(int));
    int*      rowptr   = (int*)take((size_t)(n + 1) * sizeof(int));
    int*      rowptrLo = (int*)take((size_t)n * sizeof(int));
    int*      partial  = (int*)take(512 * sizeof(int));
    int*      sedge    = (int*)take((size_t)e * sizeof(int));
    int*      adj      = (int*)take((size_t)(e + 8 * n) * sizeof(int));
    float*    uws      = (float*)take((size_t)n * 16 * sizeof(float));
    float*    uout     = (float*)d_out;

    const int gn  = (n + NB - 1) / NB;       // 391
    const int gn4 = (n * 4 + NB - 1) / NB;   // 1563
    const int gre = (e + CH - 1) / CH;       // 782
    const int gz  = (((nsb > nm) ? nsb : nm) + NB - 1) / NB;

    k_zero<<<gz, NB, 0, stream>>>(sbhist, mask, nsb, nm);
    k_hist<<<512, NB, 0, stream>>>(dst, e, sbhist, nsb);
    k_scan_sb<<<1, NSBP, 0, stream>>>(sbhist, sbbase, bcur, nsb);
    k_reorder<<<gre, RT, 0, stream>>>(src, dst, e, bcur, sedge);
    k_fine_cnt<<<nsb, SBSIZE, 0, stream>>>(sedge, sbbase, cnt, cntLo, partial, n, half);
    k_scan2<<<1, 512, 0, stream>>>(partial, gn);
    k_scan3<<<gn, NB, 0, stream>>>(cnt, cntLo, partial, rowptr, rowptrLo, n);
    k_place<<<nsb, SBSIZE, 0, stream>>>(sedge, sbbase, rowptr, rowptrLo, cnt, mask, adj, n, half);
    k_init_u<<<gn4, NB, 0, stream>>>((const v4f*)x, cnt, (v4f*)uout, n * 4);

    float* cur = uout;   // 12 layers (even) -> result ends in d_out
    float* nxt = uws;
    for (int l = 0; l < 12; ++l) {
        k_layerA<<<gn4, NB, 0, stream>>>(rowptr, rowptrLo, adj,
                                         (const v4f*)cur, (v4f*)nxt, n);
        k_layerB<<<gn4, NB, 0, stream>>>(rowptr, rowptrLo, cnt, adj,
                                         (const v4f*)cur, (v4f*)nxt, n);
        float* tp = cur; cur = nxt; nxt = tp;
    }
    k_finish<<<gn4, NB, 0, stream>>>((v4f*)uout, cnt, mask, n * 4);
}

// Round 15
// 414.142 us; speedup vs baseline: 8.8693x; 1.2698x over previous
//
#include <hip/hip_runtime.h>
#include <hip/hip_fp16.h>

// h <- A_norm h, 12 times, in u-space (u = rsqrt(deg).*h),  h12 = sqrt(deg).*u12
// State table stored FP16: [n][16] fp16 = 3.2MB -> entire table fits one XCD
// L2 (4MB), so the 8x-XCD compulsory replication halves vs f32 and capacity
// misses vanish without any split passes. Accumulation in f32 (error ~1e-5,
// 10x under threshold: contraction lambda2~0.35 + decaying |u_k|).
// CSR built per call (bucketed, atomic-light, R12 structure).
// Isolated nodes zeroed at the END (they never propagate -> equivalent).

#define NB 256
#define SBSHIFT 8
#define SBSIZE 256
#define NSBP 512          // padded bin count (nsb = ceil(n/256) = 391 <= 512)
#define CH 4096           // edges per reorder chunk
#define RT 512            // reorder threads
#define EPT 8             // CH / RT

typedef int   v4i __attribute__((ext_vector_type(4)));
typedef float v4f __attribute__((ext_vector_type(4)));

__device__ __forceinline__ float2 h2lo(unsigned w) {
    __half2 h = *reinterpret_cast<__half2*>(&w);
    return __half22float2(h);
}
__device__ __forceinline__ unsigned f2h(float a, float b) {
    __half2 h = __floats2half2_rn(a, b);
    return *reinterpret_cast<unsigned*>(&h);
}

__global__ void k_zero(int* __restrict__ sbhist, unsigned* __restrict__ mask, int nsb, int nm) {
    int i = blockIdx.x * NB + threadIdx.x;
    if (i < nsb) sbhist[i] = 0;
    if (i < nm) mask[i] = 0u;
}

__global__ void k_hist(const int* __restrict__ dst, int e, int* __restrict__ sbhist, int nsb) {
    __shared__ int lh[NSBP];
    for (int b = threadIdx.x; b < NSBP; b += NB) lh[b] = 0;
    __syncthreads();
    int stride = gridDim.x * NB;
    for (int i = blockIdx.x * NB + threadIdx.x; i < e; i += stride)
        atomicAdd(&lh[dst[i] >> SBSHIFT], 1);
    __syncthreads();
    for (int b = threadIdx.x; b < nsb; b += NB)
        if (lh[b]) atomicAdd(&sbhist[b], lh[b]);
}

__global__ __launch_bounds__(NSBP) void k_scan_sb(const int* __restrict__ sbhist,
                                                  int* __restrict__ sbbase,
                                                  int* __restrict__ bcur, int nsb) {
    __shared__ int sh[NSBP];
    int t = threadIdx.x;
    int v = (t < nsb) ? sbhist[t] : 0;
    sh[t] = v;
    __syncthreads();
    for (int off = 1; off < NSBP; off <<= 1) {
        int add = (t >= off) ? sh[t - off] : 0;
        __syncthreads();
        sh[t] += add;
        __syncthreads();
    }
    int incl = sh[t];
    if (t < nsb) { sbbase[t] = incl - v; bcur[t] = incl - v; }
    if (t == nsb - 1) sbbase[nsb] = incl;
}

// chunk-staged reorder: sedge[pos] = (src<<8)|(dst&255), bucket-sorted
__global__ __launch_bounds__(RT) void k_reorder(const int* __restrict__ src,
                                                const int* __restrict__ dst, int e,
                                                int* __restrict__ bcur, int* __restrict__ sedge) {
    __shared__ int lsize[NSBP];
    __shared__ int lscan[NSBP];
    __shared__ int ldelta[NSBP];
    __shared__ int lcur[NSBP];
    __shared__ int stage[CH];
    __shared__ int gpos[CH];
    int t = threadIdx.x;
    int base = blockIdx.x * CH;
    int cnt_here = e - base; if (cnt_here > CH) cnt_here = CH;
    lsize[t] = 0;
    __syncthreads();
    int myb[EPT], myw[EPT];
#pragma unroll
    for (int k = 0; k < EPT; ++k) {
        int i = base + k * RT + t;
        if (i < e) {
            int s = src[i], d = dst[i];
            int b = d >> SBSHIFT;
            myb[k] = b;
            myw[k] = (s << SBSHIFT) | (d & (SBSIZE - 1));
            atomicAdd(&lsize[b], 1);
        } else myb[k] = -1;
    }
    __syncthreads();
    int v = lsize[t];
    lscan[t] = v;
    __syncthreads();
    for (int off = 1; off < NSBP; off <<= 1) {
        int add = (t >= off) ? lscan[t - off] : 0;
        __syncthreads();
        lscan[t] += add;
        __syncthreads();
    }
    int excl = lscan[t] - v;
    if (v > 0) ldelta[t] = atomicAdd(&bcur[t], v) - excl;
    lcur[t] = excl;
    __syncthreads();
#pragma unroll
    for (int k = 0; k < EPT; ++k) {
        int b = myb[k];
        if (b >= 0) {
            int sl = atomicAdd(&lcur[b], 1);
            stage[sl] = myw[k];
            gpos[sl] = ldelta[b] + sl;
        }
    }
    __syncthreads();
    for (int s2 = t; s2 < cnt_here; s2 += RT)
        sedge[gpos[s2]] = stage[s2];
}

// per-bucket degree count + fused block-reduction of padded counts (scan1)
__global__ __launch_bounds__(SBSIZE) void k_fine_cnt(const int* __restrict__ sedge,
                                                     const int* __restrict__ sbbase,
                                                     int* __restrict__ cnt,
                                                     int* __restrict__ partial, int n) {
    __shared__ int lc[SBSIZE];
    __shared__ int red[SBSIZE];
    int t = threadIdx.x;
    lc[t] = 0;
    __syncthreads();
    int lo = sbbase[blockIdx.x], hi = sbbase[blockIdx.x + 1];
    for (int i = lo + t; i < hi; i += SBSIZE)
        atomicAdd(&lc[sedge[i] & (SBSIZE - 1)], 1);
    __syncthreads();
    int node = (blockIdx.x << SBSHIFT) + t;
    int c = lc[t];
    if (node < n) cnt[node] = c;
    red[t] = (node < n) ? ((c + 3) & ~3) : 0;
    __syncthreads();
    for (int s = SBSIZE / 2; s > 0; s >>= 1) {
        if (t < s) red[t] += red[t + s];
        __syncthreads();
    }
    if (t == 0) partial[blockIdx.x] = red[0];
}

__global__ void k_scan2(int* __restrict__ partial, int nb) {
    __shared__ int sd[512];
    int t = threadIdx.x;
    int v = (t < nb) ? partial[t] : 0;
    sd[t] = v;
    __syncthreads();
    for (int off = 1; off < 512; off <<= 1) {
        int add = (t >= off) ? sd[t - off] : 0;
        __syncthreads();
        sd[t] += add;
        __syncthreads();
    }
    if (t < nb) partial[t] = sd[t] - v;   // exclusive
}

__global__ void k_scan3(const int* __restrict__ cnt, const int* __restrict__ partial,
                        int* __restrict__ rowptr, int n) {
    __shared__ int sd[NB];
    int i = blockIdx.x * NB + threadIdx.x;
    int v = (i < n) ? ((cnt[i] + 3) & ~3) : 0;
    sd[threadIdx.x] = v;
    __syncthreads();
    for (int off = 1; off < NB; off <<= 1) {
        int add = (threadIdx.x >= off) ? sd[threadIdx.x - off] : 0;
        __syncthreads();
        sd[threadIdx.x] += add;
        __syncthreads();
    }
    int ex = sd[threadIdx.x] - v + partial[blockIdx.x];
    if (i < n) rowptr[i] = ex;
    if (i == n - 1) rowptr[n] = ex + v;
}

// per-bucket place via LDS cursors; pad slots filled in epilogue
__global__ __launch_bounds__(SBSIZE) void k_place(const int* __restrict__ sedge,
                                                  const int* __restrict__ sbbase,
                                                  const int* __restrict__ rowptr,
                                                  const int* __restrict__ cnt,
                                                  unsigned* __restrict__ mask,
                                                  int* __restrict__ adj, int n) {
    __shared__ int lcur[SBSIZE];
    int t = threadIdx.x;
    int node = (blockIdx.x << SBSHIFT) + t;
    lcur[t] = (node < n) ? rowptr[node] : 0;
    __syncthreads();
    int lo = sbbase[blockIdx.x], hi = sbbase[blockIdx.x + 1];
    for (int i = lo + t; i < hi; i += SBSIZE) {
        int w = sedge[i];
        int d = w & (SBSIZE - 1);
        int s = w >> SBSHIFT;
        int pos = atomicAdd(&lcur[d], 1);
        adj[pos] = s;
        if (cnt[s] == 0) atomicOr(&mask[s >> 5], 1u << (s & 31));  // rare
    }
    __syncthreads();
    if (node < n) {
        int en = rowptr[node + 1];
        for (int p = lcur[t]; p < en; ++p) adj[p] = node;  // lcur[t]==rowptr+cnt
    }
}

// u0 = fp16(x * rsqrt(deg)); lane q owns feats 4q..4q+3 (one uint2 = 4 fp16)
__global__ void k_init_u(const v4f* __restrict__ x, const int* __restrict__ cnt,
                         uint2* __restrict__ u, int n4) {
    int i = blockIdx.x * NB + threadIdx.x;
    if (i >= n4) return;
    int node = i >> 2;
    float is = rsqrtf((float)(cnt[node] + 1));
    v4f v = x[i] * is;
    uint2 w;
    w.x = f2h(v.x, v.y);
    w.y = f2h(v.z, v.w);
    u[i] = w;
}

// 4 threads per node; lane q owns 4 fp16 feats (8B gather). 8 gathers in flight.
__global__ void k_layer(const int* __restrict__ rowptr, const int* __restrict__ cnt,
                        const int* __restrict__ adj,
                        const uint2* __restrict__ u, uint2* __restrict__ un, int n) {
    int t = blockIdx.x * NB + threadIdx.x;
    int node = t >> 2, q = t & 3;
    if (node >= n) return;
    int beg = rowptr[node], endp = rowptr[node + 1];
    int deg = cnt[node];
    float corr = (float)(1 - (endp - beg - deg));   // 1 - pads
    float c0 = 1.0f / (float)(deg + 1);
    uint2 sw = u[(size_t)node * 4 + q];
    float2 s01 = h2lo(sw.x), s23 = h2lo(sw.y);
    float a0 = 0.f, a1 = 0.f, a2 = 0.f, a3 = 0.f;
    float b0 = 0.f, b1 = 0.f, b2 = 0.f, b3 = 0.f;
    int p = beg;
    for (; p + 8 <= endp; p += 8) {
        v4i sa = *(const v4i*)(adj + p);
        v4i sb = *(const v4i*)(adj + p + 4);
        uint2 g0 = u[(size_t)sa.x * 4 + q];
        uint2 g1 = u[(size_t)sa.y * 4 + q];
        uint2 g2 = u[(size_t)sa.z * 4 + q];
        uint2 g3 = u[(size_t)sa.w * 4 + q];
        uint2 g4 = u[(size_t)sb.x * 4 + q];
        uint2 g5 = u[(size_t)sb.y * 4 + q];
        uint2 g6 = u[(size_t)sb.z * 4 + q];
        uint2 g7 = u[(size_t)sb.w * 4 + q];
        float2 f;
        f = h2lo(g0.x); a0 += f.x; a1 += f.y;  f = h2lo(g0.y); a2 += f.x; a3 += f.y;
        f = h2lo(g1.x); b0 += f.x; b1 += f.y;  f = h2lo(g1.y); b2 += f.x; b3 += f.y;
        f = h2lo(g2.x); a0 += f.x; a1 += f.y;  f = h2lo(g2.y); a2 += f.x; a3 += f.y;
        f = h2lo(g3.x); b0 += f.x; b1 += f.y;  f = h2lo(g3.y); b2 += f.x; b3 += f.y;
        f = h2lo(g4.x); a0 += f.x; a1 += f.y;  f = h2lo(g4.y); a2 += f.x; a3 += f.y;
        f = h2lo(g5.x); b0 += f.x; b1 += f.y;  f = h2lo(g5.y); b2 += f.x; b3 += f.y;
        f = h2lo(g6.x); a0 += f.x; a1 += f.y;  f = h2lo(g6.y); a2 += f.x; a3 += f.y;
        f = h2lo(g7.x); b0 += f.x; b1 += f.y;  f = h2lo(g7.y); b2 += f.x; b3 += f.y;
    }
    if (p < endp) {
        v4i sa = *(const v4i*)(adj + p);
        uint2 g0 = u[(size_t)sa.x * 4 + q];
        uint2 g1 = u[(size_t)sa.y * 4 + q];
        uint2 g2 = u[(size_t)sa.z * 4 + q];
        uint2 g3 = u[(size_t)sa.w * 4 + q];
        float2 f;
        f = h2lo(g0.x); a0 += f.x; a1 += f.y;  f = h2lo(g0.y); a2 += f.x; a3 += f.y;
        f = h2lo(g1.x); b0 += f.x; b1 += f.y;  f = h2lo(g1.y); b2 += f.x; b3 += f.y;
        f = h2lo(g2.x); a0 += f.x; a1 += f.y;  f = h2lo(g2.y); a2 += f.x; a3 += f.y;
        f = h2lo(g3.x); b0 += f.x; b1 += f.y;  f = h2lo(g3.y); b2 += f.x; b3 += f.y;
    }
    float r0 = (a0 + b0 + corr * s01.x) * c0;
    float r1 = (a1 + b1 + corr * s01.y) * c0;
    float r2 = (a2 + b2 + corr * s23.x) * c0;
    float r3 = (a3 + b3 + corr * s23.y) * c0;
    uint2 w;
    w.x = f2h(r0, r1);
    w.y = f2h(r2, r3);
    un[(size_t)node * 4 + q] = w;
}

// h12 = sqrt(deg).*u12 (fp16 -> f32), zero if isolated
__global__ void k_finish(const uint2* __restrict__ u, v4f* __restrict__ h,
                         const int* __restrict__ cnt,
                         const unsigned* __restrict__ mask, int n4) {
    int i = blockIdx.x * NB + threadIdx.x;
    if (i >= n4) return;
    int node = i >> 2;
    int c = cnt[node];
    bool nonisol = (c > 0) || (((mask[node >> 5] >> (node & 31)) & 1u) != 0u);
    float s = nonisol ? sqrtf((float)(c + 1)) : 0.0f;
    uint2 w = u[i];
    float2 f01 = h2lo(w.x), f23 = h2lo(w.y);
    v4f r;
    r.x = f01.x * s; r.y = f01.y * s; r.z = f23.x * s; r.w = f23.y * s;
    h[i] = r;
}

extern "C" void kernel_launch(void* const* d_in, const int* in_sizes, int n_in,
                              void* d_out, int out_size, void* d_ws, size_t ws_size,
                              hipStream_t stream) {
    const float* x  = (const float*)d_in[0];
    const int*   ei = (const int*)d_in[1];
    const int n = in_sizes[0] / 16;   // 100000
    const int e = in_sizes[1] / 2;    // 3200000
    const int* src = ei;
    const int* dst = ei + e;
    const int nm  = (n + 31) / 32;
    const int nsb = (n + SBSIZE - 1) >> SBSHIFT;   // 391

    char* ws = (char*)d_ws;
    auto take = [&](size_t bytes) {
        char* p = ws;
        ws += (bytes + 255) & ~(size_t)255;
        return p;
    };
    int*      sbhist  = (int*)take((size_t)NSBP * sizeof(int));
    int*      sbbase  = (int*)take((size_t)(NSBP + 1) * sizeof(int));
    int*      bcur    = (int*)take((size_t)NSBP * sizeof(int));
    unsigned* mask    = (unsigned*)take((size_t)nm * sizeof(unsigned));
    int*      cnt     = (int*)take((size_t)n * sizeof(int));
    int*      rowptr  = (int*)take((size_t)(n + 1) * sizeof(int));
    int*      partial = (int*)take(512 * sizeof(int));
    int*      sedge   = (int*)take((size_t)e * sizeof(int));
    int*      adj     = (int*)take((size_t)(e + 4 * n) * sizeof(int));
    uint2*    uh0     = (uint2*)take((size_t)n * 16 * sizeof(__half));  // 3.2MB
    uint2*    uh1     = (uint2*)take((size_t)n * 16 * sizeof(__half));  // 3.2MB

    const int gn  = (n + NB - 1) / NB;       // 391
    const int gn4 = (n * 4 + NB - 1) / NB;   // 1563
    const int gre = (e + CH - 1) / CH;       // 782
    const int gz  = (((nsb > nm) ? nsb : nm) + NB - 1) / NB;

    k_zero<<<gz, NB, 0, stream>>>(sbhist, mask, nsb, nm);
    k_hist<<<512, NB, 0, stream>>>(dst, e, sbhist, nsb);
    k_scan_sb<<<1, NSBP, 0, stream>>>(sbhist, sbbase, bcur, nsb);
    k_reorder<<<gre, RT, 0, stream>>>(src, dst, e, bcur, sedge);
    k_fine_cnt<<<nsb, SBSIZE, 0, stream>>>(sedge, sbbase, cnt, partial, n);
    k_scan2<<<1, 512, 0, stream>>>(partial, gn);
    k_scan3<<<gn, NB, 0, stream>>>(cnt, partial, rowptr, n);
    k_place<<<nsb, SBSIZE, 0, stream>>>(sedge, sbbase, rowptr, cnt, mask, adj, n);
    k_init_u<<<gn4, NB, 0, stream>>>((const v4f*)x, cnt, uh0, n * 4);

    uint2* cur = uh0;   // 12 layers (even) -> final u back in uh0
    uint2* nxt = uh1;
    for (int l = 0; l < 12; ++l) {
        k_layer<<<gn4, NB, 0, stream>>>(rowptr, cnt, adj, cur, nxt, n);
        uint2* tp = cur; cur = nxt; nxt = tp;
    }
    k_finish<<<gn4, NB, 0, stream>>>(cur, (v4f*)d_out, cnt, mask, n * 4);
}

// Round 17
// 412.439 us; speedup vs baseline: 8.9059x; 1.0041x over previous
//
#include <hip/hip_runtime.h>
#include <hip/hip_fp16.h>

// h <- A_norm h, 12 times, in u-space (u = rsqrt(deg).*h),  h12 = sqrt(deg).*u12
// State table stored FP16: [n][16] fp16 = 3.2MB -> entire table fits one XCD
// L2 (4MB), so the 8x-XCD compulsory replication halves vs f32 and capacity
// misses vanish without any split passes. Accumulation in f32 (error ~6e-5,
// 3x under threshold: contraction lambda2~0.35 + decaying |u_k|).
// CSR built per call (bucketed, atomic-light, R12 structure).
// Isolated nodes zeroed at the END (they never propagate -> equivalent).
// R16's cooperative-kernel fusion failed (silent launch rejection) -> this is
// the proven R15 champion, byte-identical.

#define NB 256
#define SBSHIFT 8
#define SBSIZE 256
#define NSBP 512          // padded bin count (nsb = ceil(n/256) = 391 <= 512)
#define CH 4096           // edges per reorder chunk
#define RT 512            // reorder threads
#define EPT 8             // CH / RT

typedef int   v4i __attribute__((ext_vector_type(4)));
typedef float v4f __attribute__((ext_vector_type(4)));

__device__ __forceinline__ float2 h2lo(unsigned w) {
    __half2 h = *reinterpret_cast<__half2*>(&w);
    return __half22float2(h);
}
__device__ __forceinline__ unsigned f2h(float a, float b) {
    __half2 h = __floats2half2_rn(a, b);
    return *reinterpret_cast<unsigned*>(&h);
}

__global__ void k_zero(int* __restrict__ sbhist, unsigned* __restrict__ mask, int nsb, int nm) {
    int i = blockIdx.x * NB + threadIdx.x;
    if (i < nsb) sbhist[i] = 0;
    if (i < nm) mask[i] = 0u;
}

__global__ void k_hist(const int* __restrict__ dst, int e, int* __restrict__ sbhist, int nsb) {
    __shared__ int lh[NSBP];
    for (int b = threadIdx.x; b < NSBP; b += NB) lh[b] = 0;
    __syncthreads();
    int stride = gridDim.x * NB;
    for (int i = blockIdx.x * NB + threadIdx.x; i < e; i += stride)
        atomicAdd(&lh[dst[i] >> SBSHIFT], 1);
    __syncthreads();
    for (int b = threadIdx.x; b < nsb; b += NB)
        if (lh[b]) atomicAdd(&sbhist[b], lh[b]);
}

__global__ __launch_bounds__(NSBP) void k_scan_sb(const int* __restrict__ sbhist,
                                                  int* __restrict__ sbbase,
                                                  int* __restrict__ bcur, int nsb) {
    __shared__ int sh[NSBP];
    int t = threadIdx.x;
    int v = (t < nsb) ? sbhist[t] : 0;
    sh[t] = v;
    __syncthreads();
    for (int off = 1; off < NSBP; off <<= 1) {
        int add = (t >= off) ? sh[t - off] : 0;
        __syncthreads();
        sh[t] += add;
        __syncthreads();
    }
    int incl = sh[t];
    if (t < nsb) { sbbase[t] = incl - v; bcur[t] = incl - v; }
    if (t == nsb - 1) sbbase[nsb] = incl;
}

// chunk-staged reorder: sedge[pos] = (src<<8)|(dst&255), bucket-sorted
__global__ __launch_bounds__(RT) void k_reorder(const int* __restrict__ src,
                                                const int* __restrict__ dst, int e,
                                                int* __restrict__ bcur, int* __restrict__ sedge) {
    __shared__ int lsize[NSBP];
    __shared__ int lscan[NSBP];
    __shared__ int ldelta[NSBP];
    __shared__ int lcur[NSBP];
    __shared__ int stage[CH];
    __shared__ int gpos[CH];
    int t = threadIdx.x;
    int base = blockIdx.x * CH;
    int cnt_here = e - base; if (cnt_here > CH) cnt_here = CH;
    lsize[t] = 0;
    __syncthreads();
    int myb[EPT], myw[EPT];
#pragma unroll
    for (int k = 0; k < EPT; ++k) {
        int i = base + k * RT + t;
        if (i < e) {
            int s = src[i], d = dst[i];
            int b = d >> SBSHIFT;
            myb[k] = b;
            myw[k] = (s << SBSHIFT) | (d & (SBSIZE - 1));
            atomicAdd(&lsize[b], 1);
        } else myb[k] = -1;
    }
    __syncthreads();
    int v = lsize[t];
    lscan[t] = v;
    __syncthreads();
    for (int off = 1; off < NSBP; off <<= 1) {
        int add = (t >= off) ? lscan[t - off] : 0;
        __syncthreads();
        lscan[t] += add;
        __syncthreads();
    }
    int excl = lscan[t] - v;
    if (v > 0) ldelta[t] = atomicAdd(&bcur[t], v) - excl;
    lcur[t] = excl;
    __syncthreads();
#pragma unroll
    for (int k = 0; k < EPT; ++k) {
        int b = myb[k];
        if (b >= 0) {
            int sl = atomicAdd(&lcur[b], 1);
            stage[sl] = myw[k];
            gpos[sl] = ldelta[b] + sl;
        }
    }
    __syncthreads();
    for (int s2 = t; s2 < cnt_here; s2 += RT)
        sedge[gpos[s2]] = stage[s2];
}

// per-bucket degree count + fused block-reduction of padded counts (scan1)
__global__ __launch_bounds__(SBSIZE) void k_fine_cnt(const int* __restrict__ sedge,
                                                     const int* __restrict__ sbbase,
                                                     int* __restrict__ cnt,
                                                     int* __restrict__ partial, int n) {
    __shared__ int lc[SBSIZE];
    __shared__ int red[SBSIZE];
    int t = threadIdx.x;
    lc[t] = 0;
    __syncthreads();
    int lo = sbbase[blockIdx.x], hi = sbbase[blockIdx.x + 1];
    for (int i = lo + t; i < hi; i += SBSIZE)
        atomicAdd(&lc[sedge[i] & (SBSIZE - 1)], 1);
    __syncthreads();
    int node = (blockIdx.x << SBSHIFT) + t;
    int c = lc[t];
    if (node < n) cnt[node] = c;
    red[t] = (node < n) ? ((c + 3) & ~3) : 0;
    __syncthreads();
    for (int s = SBSIZE / 2; s > 0; s >>= 1) {
        if (t < s) red[t] += red[t + s];
        __syncthreads();
    }
    if (t == 0) partial[blockIdx.x] = red[0];
}

__global__ void k_scan2(int* __restrict__ partial, int nb) {
    __shared__ int sd[512];
    int t = threadIdx.x;
    int v = (t < nb) ? partial[t] : 0;
    sd[t] = v;
    __syncthreads();
    for (int off = 1; off < 512; off <<= 1) {
        int add = (t >= off) ? sd[t - off] : 0;
        __syncthreads();
        sd[t] += add;
        __syncthreads();
    }
    if (t < nb) partial[t] = sd[t] - v;   // exclusive
}

__global__ void k_scan3(const int* __restrict__ cnt, const int* __restrict__ partial,
                        int* __restrict__ rowptr, int n) {
    __shared__ int sd[NB];
    int i = blockIdx.x * NB + threadIdx.x;
    int v = (i < n) ? ((cnt[i] + 3) & ~3) : 0;
    sd[threadIdx.x] = v;
    __syncthreads();
    for (int off = 1; off < NB; off <<= 1) {
        int add = (threadIdx.x >= off) ? sd[threadIdx.x - off] : 0;
        __syncthreads();
        sd[threadIdx.x] += add;
        __syncthreads();
    }
    int ex = sd[threadIdx.x] - v + partial[blockIdx.x];
    if (i < n) rowptr[i] = ex;
    if (i == n - 1) rowptr[n] = ex + v;
}

// per-bucket place via LDS cursors; pad slots filled in epilogue
__global__ __launch_bounds__(SBSIZE) void k_place(const int* __restrict__ sedge,
                                                  const int* __restrict__ sbbase,
                                                  const int* __restrict__ rowptr,
                                                  const int* __restrict__ cnt,
                                                  unsigned* __restrict__ mask,
                                                  int* __restrict__ adj, int n) {
    __shared__ int lcur[SBSIZE];
    int t = threadIdx.x;
    int node = (blockIdx.x << SBSHIFT) + t;
    lcur[t] = (node < n) ? rowptr[node] : 0;
    __syncthreads();
    int lo = sbbase[blockIdx.x], hi = sbbase[blockIdx.x + 1];
    for (int i = lo + t; i < hi; i += SBSIZE) {
        int w = sedge[i];
        int d = w & (SBSIZE - 1);
        int s = w >> SBSHIFT;
        int pos = atomicAdd(&lcur[d], 1);
        adj[pos] = s;
        if (cnt[s] == 0) atomicOr(&mask[s >> 5], 1u << (s & 31));  // rare
    }
    __syncthreads();
    if (node < n) {
        int en = rowptr[node + 1];
        for (int p = lcur[t]; p < en; ++p) adj[p] = node;  // lcur[t]==rowptr+cnt
    }
}

// u0 = fp16(x * rsqrt(deg)); lane q owns feats 4q..4q+3 (one uint2 = 4 fp16)
__global__ void k_init_u(const v4f* __restrict__ x, const int* __restrict__ cnt,
                         uint2* __restrict__ u, int n4) {
    int i = blockIdx.x * NB + threadIdx.x;
    if (i >= n4) return;
    int node = i >> 2;
    float is = rsqrtf((float)(cnt[node] + 1));
    v4f v = x[i] * is;
    uint2 w;
    w.x = f2h(v.x, v.y);
    w.y = f2h(v.z, v.w);
    u[i] = w;
}

// 4 threads per node; lane q owns 4 fp16 feats (8B gather). 8 gathers in flight.
__global__ void k_layer(const int* __restrict__ rowptr, const int* __restrict__ cnt,
                        const int* __restrict__ adj,
                        const uint2* __restrict__ u, uint2* __restrict__ un, int n) {
    int t = blockIdx.x * NB + threadIdx.x;
    int node = t >> 2, q = t & 3;
    if (node >= n) return;
    int beg = rowptr[node], endp = rowptr[node + 1];
    int deg = cnt[node];
    float corr = (float)(1 - (endp - beg - deg));   // 1 - pads
    float c0 = 1.0f / (float)(deg + 1);
    uint2 sw = u[(size_t)node * 4 + q];
    float2 s01 = h2lo(sw.x), s23 = h2lo(sw.y);
    float a0 = 0.f, a1 = 0.f, a2 = 0.f, a3 = 0.f;
    float b0 = 0.f, b1 = 0.f, b2 = 0.f, b3 = 0.f;
    int p = beg;
    for (; p + 8 <= endp; p += 8) {
        v4i sa = *(const v4i*)(adj + p);
        v4i sb = *(const v4i*)(adj + p + 4);
        uint2 g0 = u[(size_t)sa.x * 4 + q];
        uint2 g1 = u[(size_t)sa.y * 4 + q];
        uint2 g2 = u[(size_t)sa.z * 4 + q];
        uint2 g3 = u[(size_t)sa.w * 4 + q];
        uint2 g4 = u[(size_t)sb.x * 4 + q];
        uint2 g5 = u[(size_t)sb.y * 4 + q];
        uint2 g6 = u[(size_t)sb.z * 4 + q];
        uint2 g7 = u[(size_t)sb.w * 4 + q];
        float2 f;
        f = h2lo(g0.x); a0 += f.x; a1 += f.y;  f = h2lo(g0.y); a2 += f.x; a3 += f.y;
        f = h2lo(g1.x); b0 += f.x; b1 += f.y;  f = h2lo(g1.y); b2 += f.x; b3 += f.y;
        f = h2lo(g2.x); a0 += f.x; a1 += f.y;  f = h2lo(g2.y); a2 += f.x; a3 += f.y;
        f = h2lo(g3.x); b0 += f.x; b1 += f.y;  f = h2lo(g3.y); b2 += f.x; b3 += f.y;
        f = h2lo(g4.x); a0 += f.x; a1 += f.y;  f = h2lo(g4.y); a2 += f.x; a3 += f.y;
        f = h2lo(g5.x); b0 += f.x; b1 += f.y;  f = h2lo(g5.y); b2 += f.x; b3 += f.y;
        f = h2lo(g6.x); a0 += f.x; a1 += f.y;  f = h2lo(g6.y); a2 += f.x; a3 += f.y;
        f = h2lo(g7.x); b0 += f.x; b1 += f.y;  f = h2lo(g7.y); b2 += f.x; b3 += f.y;
    }
    if (p < endp) {
        v4i sa = *(const v4i*)(adj + p);
        uint2 g0 = u[(size_t)sa.x * 4 + q];
        uint2 g1 = u[(size_t)sa.y * 4 + q];
        uint2 g2 = u[(size_t)sa.z * 4 + q];
        uint2 g3 = u[(size_t)sa.w * 4 + q];
        float2 f;
        f = h2lo(g0.x); a0 += f.x; a1 += f.y;  f = h2lo(g0.y); a2 += f.x; a3 += f.y;
        f = h2lo(g1.x); b0 += f.x; b1 += f.y;  f = h2lo(g1.y); b2 += f.x; b3 += f.y;
        f = h2lo(g2.x); a0 += f.x; a1 += f.y;  f = h2lo(g2.y); a2 += f.x; a3 += f.y;
        f = h2lo(g3.x); b0 += f.x; b1 += f.y;  f = h2lo(g3.y); b2 += f.x; b3 += f.y;
    }
    float r0 = (a0 + b0 + corr * s01.x) * c0;
    float r1 = (a1 + b1 + corr * s01.y) * c0;
    float r2 = (a2 + b2 + corr * s23.x) * c0;
    float r3 = (a3 + b3 + corr * s23.y) * c0;
    uint2 w;
    w.x = f2h(r0, r1);
    w.y = f2h(r2, r3);
    un[(size_t)node * 4 + q] = w;
}

// h12 = sqrt(deg).*u12 (fp16 -> f32), zero if isolated
__global__ void k_finish(const uint2* __restrict__ u, v4f* __restrict__ h,
                         const int* __restrict__ cnt,
                         const unsigned* __restrict__ mask, int n4) {
    int i = blockIdx.x * NB + threadIdx.x;
    if (i >= n4) return;
    int node = i >> 2;
    int c = cnt[node];
    bool nonisol = (c > 0) || (((mask[node >> 5] >> (node & 31)) & 1u) != 0u);
    float s = nonisol ? sqrtf((float)(c + 1)) : 0.0f;
    uint2 w = u[i];
    float2 f01 = h2lo(w.x), f23 = h2lo(w.y);
    v4f r;
    r.x = f01.x * s; r.y = f01.y * s; r.z = f23.x * s; r.w = f23.y * s;
    h[i] = r;
}

extern "C" void kernel_launch(void* const* d_in, const int* in_sizes, int n_in,
                              void* d_out, int out_size, void* d_ws, size_t ws_size,
                              hipStream_t stream) {
    const float* x  = (const float*)d_in[0];
    const int*   ei = (const int*)d_in[1];
    const int n = in_sizes[0] / 16;   // 100000
    const int e = in_sizes[1] / 2;    // 3200000
    const int* src = ei;
    const int* dst = ei + e;
    const int nm  = (n + 31) / 32;
    const int nsb = (n + SBSIZE - 1) >> SBSHIFT;   // 391

    char* ws = (char*)d_ws;
    auto take = [&](size_t bytes) {
        char* p = ws;
        ws += (bytes + 255) & ~(size_t)255;
        return p;
    };
    int*      sbhist  = (int*)take((size_t)NSBP * sizeof(int));
    int*      sbbase  = (int*)take((size_t)(NSBP + 1) * sizeof(int));
    int*      bcur    = (int*)take((size_t)NSBP * sizeof(int));
    unsigned* mask    = (unsigned*)take((size_t)nm * sizeof(unsigned));
    int*      cnt     = (int*)take((size_t)n * sizeof(int));
    int*      rowptr  = (int*)take((size_t)(n + 1) * sizeof(int));
    int*      partial = (int*)take(512 * sizeof(int));
    int*      sedge   = (int*)take((size_t)e * sizeof(int));
    int*      adj     = (int*)take((size_t)(e + 4 * n) * sizeof(int));
    uint2*    uh0     = (uint2*)take((size_t)n * 16 * sizeof(__half));  // 3.2MB
    uint2*    uh1     = (uint2*)take((size_t)n * 16 * sizeof(__half));  // 3.2MB

    const int gn  = (n + NB - 1) / NB;       // 391
    const int gn4 = (n * 4 + NB - 1) / NB;   // 1563
    const int gre = (e + CH - 1) / CH;       // 782
    const int gz  = (((nsb > nm) ? nsb : nm) + NB - 1) / NB;

    k_zero<<<gz, NB, 0, stream>>>(sbhist, mask, nsb, nm);
    k_hist<<<512, NB, 0, stream>>>(dst, e, sbhist, nsb);
    k_scan_sb<<<1, NSBP, 0, stream>>>(sbhist, sbbase, bcur, nsb);
    k_reorder<<<gre, RT, 0, stream>>>(src, dst, e, bcur, sedge);
    k_fine_cnt<<<nsb, SBSIZE, 0, stream>>>(sedge, sbbase, cnt, partial, n);
    k_scan2<<<1, 512, 0, stream>>>(partial, gn);
    k_scan3<<<gn, NB, 0, stream>>>(cnt, partial, rowptr, n);
    k_place<<<nsb, SBSIZE, 0, stream>>>(sedge, sbbase, rowptr, cnt, mask, adj, n);
    k_init_u<<<gn4, NB, 0, stream>>>((const v4f*)x, cnt, uh0, n * 4);

    uint2* cur = uh0;   // 12 layers (even) -> final u back in uh0
    uint2* nxt = uh1;
    for (int l = 0; l < 12; ++l) {
        k_layer<<<gn4, NB, 0, stream>>>(rowptr, cnt, adj, cur, nxt, n);
        uint2* tp = cur; cur = nxt; nxt = tp;
    }
    k_finish<<<gn4, NB, 0, stream>>>(cur, (v4f*)d_out, cnt, mask, n * 4);
}